// Round 1
// baseline (5287.385 us; speedup 1.0000x reference)
//
#include <hip/hip_runtime.h>
#include <hip/hip_bf16.h>

#define D 256
#define NH 4
#define HD 64
#define NL 8
#define DFF 1024
#define VOCAB 100
#define LT 256
#define BB 2
#define FH 32
#define FW 256
#define S_MEM (FH*FW)        // 8192
#define NTOK (LT*BB)         // 512 token rows
#define MEMROWS (BB*S_MEM)   // 16384 memory rows
#define EPS 1e-5f

// ---------------------------------------------------------------------------
// mem = features + PE2D, transposed (B,C,H,W) -> [B][S=H*W][C]
// ---------------------------------------------------------------------------
__global__ __launch_bounds__(256) void build_mem_kernel(const float* __restrict__ f,
                                                        float* __restrict__ memb)
{
    __shared__ float tile[32][33];
    int wt = blockIdx.x * 32, ct = blockIdx.y * 32;
    int b = blockIdx.z >> 5, h = blockIdx.z & 31;
    int tx = threadIdx.x, ty = threadIdx.y;  // 32 x 8
#pragma unroll
    for (int p = 0; p < 4; ++p) {
        int c = ty + p * 8;
        tile[c][tx] = f[(((size_t)(b * D + ct + c)) * FH + h) * FW + wt + tx];
    }
    __syncthreads();
#pragma unroll
    for (int p = 0; p < 4; ++p) {
        int wl = ty + p * 8;
        int c = ct + tx;
        int w = wt + wl;
        int j2 = (c & 127) & ~1;                // 2*j
        float dv = expf(-((float)j2 * (1.f / 256.f)) * 9.210340371976184f);
        float pos = (c < 128) ? (float)h : (float)w;
        float ang = pos * dv;
        float pe = (c & 1) ? cosf(ang) : sinf(ang);
        memb[((size_t)b * S_MEM + (size_t)h * FW + w) * D + c] = tile[tx][wl] + pe;
    }
}

// ---------------------------------------------------------------------------
// tgt = emb[tokens] + PE1D, layout [L][B][D] rows = l*B+b
// ---------------------------------------------------------------------------
__global__ __launch_bounds__(256) void embed_kernel(const int* __restrict__ tokens,
                                                    const float* __restrict__ emb,
                                                    float* __restrict__ tgt)
{
    int r = blockIdx.x;       // l*B+b
    int d = threadIdx.x;
    int l = r >> 1;
    int tok = tokens[r];
    int j2 = d & ~1;          // 2*j
    float dv = expf(-((float)j2 * (1.f / 256.f)) * 9.210340371976184f);
    float ang = (float)l * dv;
    float pe = (d & 1) ? cosf(ang) : sinf(ang);
    tgt[(size_t)r * D + d] = emb[(size_t)tok * D + d] + pe;
}

// ---------------------------------------------------------------------------
// C[M,N] = A[M,K] @ W[N,K]^T + bias[N]  (optional ReLU)
// 64x64 tile, 256 threads, strided 4x4 per thread; float4 LDS inner reads.
// M % 64 == 0, K % 32 == 0; N guarded.
// ---------------------------------------------------------------------------
#define GKT 32
__global__ __launch_bounds__(256) void gemm_bias_kernel(const float* __restrict__ A,
                                                        const float* __restrict__ W,
                                                        const float* __restrict__ bias,
                                                        float* __restrict__ C,
                                                        int M, int N, int K, int relu)
{
    __shared__ float As[64][GKT + 4];
    __shared__ float Bs[64][GKT + 4];
    const int tid = threadIdx.x;
    const int tx = tid & 15, ty = tid >> 4;
    const int m0 = blockIdx.y * 64, n0 = blockIdx.x * 64;
    const int lcol = tid & 31;   // k within tile
    const int lrow = tid >> 5;   // 8 rows per pass
    float acc[4][4] = {};
    for (int k0 = 0; k0 < K; k0 += GKT) {
#pragma unroll
        for (int p = 0; p < 8; ++p) {
            int r = lrow + p * 8;
            As[r][lcol] = A[(size_t)(m0 + r) * K + k0 + lcol];
            int n = n0 + r;
            Bs[r][lcol] = (n < N) ? W[(size_t)n * K + k0 + lcol] : 0.f;
        }
        __syncthreads();
#pragma unroll
        for (int k4 = 0; k4 < GKT / 4; ++k4) {
            float4 av[4], bv[4];
#pragma unroll
            for (int i = 0; i < 4; ++i) av[i] = *(const float4*)&As[ty + 16 * i][k4 * 4];
#pragma unroll
            for (int j = 0; j < 4; ++j) bv[j] = *(const float4*)&Bs[tx + 16 * j][k4 * 4];
#pragma unroll
            for (int i = 0; i < 4; ++i)
#pragma unroll
                for (int j = 0; j < 4; ++j)
                    acc[i][j] += av[i].x * bv[j].x + av[i].y * bv[j].y +
                                 av[i].z * bv[j].z + av[i].w * bv[j].w;
        }
        __syncthreads();
    }
#pragma unroll
    for (int i = 0; i < 4; ++i) {
        int m = m0 + ty + 16 * i;
#pragma unroll
        for (int j = 0; j < 4; ++j) {
            int n = n0 + tx + 16 * j;
            if (n < N) {
                float v = acc[i][j] + bias[n];
                if (relu) v = fmaxf(v, 0.f);
                C[(size_t)m * N + n] = v;
            }
        }
    }
}

// ---------------------------------------------------------------------------
// Batched strided scores: Sc[bh][l][s] = scale * dot64(Q_bh[l], K_bh[s])
// Row of Q for (l,b,h): Q + b*qStrideB + h*64 + l*qStrideL (similarly K with s).
// ---------------------------------------------------------------------------
__global__ __launch_bounds__(256) void attn_scores_kernel(const float* __restrict__ Q,
                                                          int qStrideB, int qStrideL,
                                                          const float* __restrict__ Kp,
                                                          int kStrideB, int kStrideS,
                                                          float* __restrict__ Sc,
                                                          int Sk, float scale)
{
    __shared__ float Qs[64][68];
    __shared__ float Ks[64][68];
    int bh = blockIdx.z, b = bh >> 2, h = bh & 3;
    int l0 = blockIdx.y * 64, s0 = blockIdx.x * 64;
    const float* Qb = Q + (size_t)b * qStrideB + h * HD;
    const float* Kb = Kp + (size_t)b * kStrideB + h * HD;
    int tid = threadIdx.x;
    int lcol = tid & 63, lrow = tid >> 6;  // 4 rows/pass
#pragma unroll
    for (int p = 0; p < 16; ++p) {
        int r = lrow + p * 4;
        Qs[r][lcol] = Qb[(size_t)(l0 + r) * qStrideL + lcol];
        Ks[r][lcol] = Kb[(size_t)(s0 + r) * kStrideS + lcol];
    }
    __syncthreads();
    int tx = tid & 15, ty = tid >> 4;
    float acc[4][4] = {};
#pragma unroll
    for (int k4 = 0; k4 < 16; ++k4) {
        float4 av[4], bv[4];
#pragma unroll
        for (int i = 0; i < 4; ++i) av[i] = *(const float4*)&Qs[ty + 16 * i][k4 * 4];
#pragma unroll
        for (int j = 0; j < 4; ++j) bv[j] = *(const float4*)&Ks[tx + 16 * j][k4 * 4];
#pragma unroll
        for (int i = 0; i < 4; ++i)
#pragma unroll
            for (int j = 0; j < 4; ++j)
                acc[i][j] += av[i].x * bv[j].x + av[i].y * bv[j].y +
                             av[i].z * bv[j].z + av[i].w * bv[j].w;
    }
#pragma unroll
    for (int i = 0; i < 4; ++i) {
        size_t rowoff = ((size_t)bh * LT + l0 + ty + 16 * i) * Sk + s0;
#pragma unroll
        for (int j = 0; j < 4; ++j)
            Sc[rowoff + tx + 16 * j] = acc[i][j] * scale;
    }
}

// ---------------------------------------------------------------------------
// Row softmax in place. NIT = Sk/256 (1 for self, 32 for cross). causal masks s>l.
// Writes 0 for masked entries so PV can read the full row.
// ---------------------------------------------------------------------------
template <int NIT>
__global__ __launch_bounds__(256) void softmax_kernel(float* __restrict__ Sc, int Sk, int causal)
{
    int l = blockIdx.x, bh = blockIdx.y;
    float* row = Sc + ((size_t)bh * LT + l) * Sk;
    int valid = causal ? (l + 1) : Sk;
    int tid = threadIdx.x;
    float vals[NIT];
    float m = -3.0e38f;
#pragma unroll
    for (int i = 0; i < NIT; ++i) {
        int idx = tid + i * 256;
        float v = (idx < valid) ? row[idx] : -3.0e38f;
        vals[i] = v;
        m = fmaxf(m, v);
    }
#pragma unroll
    for (int off = 32; off; off >>= 1) m = fmaxf(m, __shfl_xor(m, off));
    __shared__ float smax[4];
    __shared__ float ssum[4];
    int lane = tid & 63, w = tid >> 6;
    if (lane == 0) smax[w] = m;
    __syncthreads();
    m = fmaxf(fmaxf(smax[0], smax[1]), fmaxf(smax[2], smax[3]));
    float s = 0.f;
#pragma unroll
    for (int i = 0; i < NIT; ++i) {
        int idx = tid + i * 256;
        float e = (idx < valid) ? __expf(vals[i] - m) : 0.f;
        vals[i] = e;
        s += e;
    }
#pragma unroll
    for (int off = 32; off; off >>= 1) s += __shfl_xor(s, off);
    if (lane == 0) ssum[w] = s;
    __syncthreads();
    s = ssum[0] + ssum[1] + ssum[2] + ssum[3];
    float inv = 1.f / s;
#pragma unroll
    for (int i = 0; i < NIT; ++i) {
        int idx = tid + i * 256;
        row[idx] = vals[i] * inv;
    }
}

// ---------------------------------------------------------------------------
// O[l, b, h*64+d] += sum_s P[bh][l][s] * V_bh[s][d]   (split-K over s chunks,
// fp32 atomics; O zeroed beforehand).
// ---------------------------------------------------------------------------
__global__ __launch_bounds__(256) void attn_pv_kernel(const float* __restrict__ P,
                                                      const float* __restrict__ V,
                                                      int vStrideB, int vStrideS,
                                                      float* __restrict__ O,
                                                      int Sk, int chunk)
{
    __shared__ float Ps[64][20];
    __shared__ float Vs[16][68];
    int bh = blockIdx.z, b = bh >> 2, h = bh & 3;
    int l0 = blockIdx.y * 64;
    int sBeg = blockIdx.x * chunk;
    const float* Pb = P + ((size_t)bh * LT + l0) * Sk;
    const float* Vb = V + (size_t)b * vStrideB + h * HD;
    int tid = threadIdx.x;
    int tx = tid & 15, ty = tid >> 4;
    float acc[4][4] = {};
    for (int s0 = sBeg; s0 < sBeg + chunk; s0 += 16) {
        {
            int lc = tid & 15, lr = tid >> 4;  // P: 16 rows/pass, 4 passes
#pragma unroll
            for (int p = 0; p < 4; ++p) {
                int r = lr + p * 16;
                Ps[r][lc] = Pb[(size_t)r * Sk + s0 + lc];
            }
            int vd = tid & 63, vs = tid >> 6;  // V: 4 rows/pass, 4 passes
#pragma unroll
            for (int p = 0; p < 4; ++p) {
                int s = vs + p * 4;
                Vs[s][vd] = Vb[(size_t)(s0 + s) * vStrideS + vd];
            }
        }
        __syncthreads();
#pragma unroll
        for (int k4 = 0; k4 < 4; ++k4) {
            float pa[4][4];
#pragma unroll
            for (int i = 0; i < 4; ++i) {
                float4 t = *(const float4*)&Ps[ty + 16 * i][k4 * 4];
                pa[i][0] = t.x; pa[i][1] = t.y; pa[i][2] = t.z; pa[i][3] = t.w;
            }
#pragma unroll
            for (int kk = 0; kk < 4; ++kk) {
                float bj[4];
#pragma unroll
                for (int j = 0; j < 4; ++j) bj[j] = Vs[k4 * 4 + kk][tx + 16 * j];
#pragma unroll
                for (int i = 0; i < 4; ++i)
#pragma unroll
                    for (int j = 0; j < 4; ++j) acc[i][j] += pa[i][kk] * bj[j];
            }
        }
        __syncthreads();
    }
#pragma unroll
    for (int i = 0; i < 4; ++i) {
        int l = l0 + ty + 16 * i;
#pragma unroll
        for (int j = 0; j < 4; ++j)
            atomicAdd(&O[((size_t)l * BB + b) * D + h * HD + tx + 16 * j], acc[i][j]);
    }
}

// ---------------------------------------------------------------------------
// tgt = LayerNorm(tgt + t2) * g + beta   (rows = NTOK, D=256, 1 block/row)
// ---------------------------------------------------------------------------
__global__ __launch_bounds__(256) void ln_kernel(float* __restrict__ tgt,
                                                 const float* __restrict__ t2,
                                                 const float* __restrict__ g,
                                                 const float* __restrict__ beta)
{
    int r = blockIdx.x, d = threadIdx.x;
    float x = tgt[(size_t)r * D + d] + t2[(size_t)r * D + d];
    float v1 = x, v2 = x * x;
#pragma unroll
    for (int off = 32; off; off >>= 1) {
        v1 += __shfl_xor(v1, off);
        v2 += __shfl_xor(v2, off);
    }
    __shared__ float s1[4], s2[4];
    int lane = d & 63, w = d >> 6;
    if (lane == 0) { s1[w] = v1; s2[w] = v2; }
    __syncthreads();
    float sum = s1[0] + s1[1] + s1[2] + s1[3];
    float sums = s2[0] + s2[1] + s2[2] + s2[3];
    float mean = sum * (1.f / 256.f);
    float var = sums * (1.f / 256.f) - mean * mean;
    tgt[(size_t)r * D + d] = (x - mean) * rsqrtf(var + EPS) * g[d] + beta[d];
}

// ---------------------------------------------------------------------------
extern "C" void kernel_launch(void* const* d_in, const int* in_sizes, int n_in,
                              void* d_out, int out_size, void* d_ws, size_t ws_size,
                              hipStream_t stream)
{
    (void)in_sizes; (void)n_in; (void)out_size; (void)ws_size;
    const int*   tokens   = (const int*)d_in[0];
    const float* features = (const float*)d_in[1];
    const float* emb      = (const float*)d_in[2];
    const float* sa_w     = (const float*)d_in[3];
    const float* sa_b     = (const float*)d_in[4];
    const float* ca_w     = (const float*)d_in[5];
    const float* ca_b     = (const float*)d_in[6];
    const float* ln_g     = (const float*)d_in[7];
    const float* ln_b     = (const float*)d_in[8];
    const float* ff_w1    = (const float*)d_in[9];
    const float* ff_b1    = (const float*)d_in[10];
    const float* ff_w2    = (const float*)d_in[11];
    const float* ff_b2    = (const float*)d_in[12];
    const float* out_w    = (const float*)d_in[13];
    const float* out_b    = (const float*)d_in[14];
    float* out = (float*)d_out;

    float* ws   = (float*)d_ws;
    float* memb = ws;                                   // 16384*256      = 4,194,304
    float* kv   = memb + (size_t)MEMROWS * D;           // 16384*512      = 8,388,608
    float* sc   = kv + (size_t)MEMROWS * 512;           // 8*256*8192     = 16,777,216
    float* tgtb = sc + (size_t)8 * LT * S_MEM;          // 512*256
    float* qkv  = tgtb + (size_t)NTOK * D;              // 512*768
    float* qc   = qkv + (size_t)NTOK * 768;             // 512*256
    float* obuf = qc + (size_t)NTOK * D;                // 512*256
    float* t2b  = obuf + (size_t)NTOK * D;              // 512*256
    float* hbuf = t2b + (size_t)NTOK * D;               // 512*1024

    const float scale = 0.125f;  // hd^-0.5

    build_mem_kernel<<<dim3(FW / 32, D / 32, BB * FH), dim3(32, 8), 0, stream>>>(features, memb);
    embed_kernel<<<NTOK, D, 0, stream>>>(tokens, emb, tgtb);

    for (int i = 0; i < NL; ++i) {
        const float* saw = sa_w + (size_t)i * 4 * D * D;
        const float* sab = sa_b + (size_t)i * 4 * D;
        const float* caw = ca_w + (size_t)i * 4 * D * D;
        const float* cab = ca_b + (size_t)i * 4 * D;
        const float* lg  = ln_g + (size_t)i * 3 * D;
        const float* lb  = ln_b + (size_t)i * 3 * D;

        // ---- self attention (causal) ----
        gemm_bias_kernel<<<dim3(768 / 64, NTOK / 64), 256, 0, stream>>>(
            tgtb, saw, sab, qkv, NTOK, 768, D, 0);
        attn_scores_kernel<<<dim3(LT / 64, LT / 64, BB * NH), 256, 0, stream>>>(
            qkv, 768, 2 * 768, qkv + 256, 768, 2 * 768, sc, LT, scale);
        softmax_kernel<1><<<dim3(LT, BB * NH), 256, 0, stream>>>(sc, LT, 1);
        hipMemsetAsync(obuf, 0, (size_t)NTOK * D * sizeof(float), stream);
        attn_pv_kernel<<<dim3(1, LT / 64, BB * NH), 256, 0, stream>>>(
            sc, qkv + 512, 768, 2 * 768, obuf, LT, LT);
        gemm_bias_kernel<<<dim3(D / 64, NTOK / 64), 256, 0, stream>>>(
            obuf, saw + 3 * D * D, sab + 3 * D, t2b, NTOK, D, D, 0);
        ln_kernel<<<NTOK, D, 0, stream>>>(tgtb, t2b, lg, lb);

        // ---- cross attention ----
        gemm_bias_kernel<<<dim3(D / 64, NTOK / 64), 256, 0, stream>>>(
            tgtb, caw, cab, qc, NTOK, D, D, 0);
        gemm_bias_kernel<<<dim3(512 / 64, MEMROWS / 64), 256, 0, stream>>>(
            memb, caw + D * D, cab + D, kv, MEMROWS, 512, D, 0);
        attn_scores_kernel<<<dim3(S_MEM / 64, LT / 64, BB * NH), 256, 0, stream>>>(
            qc, D, 2 * D, kv, S_MEM * 512, 512, sc, S_MEM, scale);
        softmax_kernel<32><<<dim3(LT, BB * NH), 256, 0, stream>>>(sc, S_MEM, 0);
        hipMemsetAsync(obuf, 0, (size_t)NTOK * D * sizeof(float), stream);
        attn_pv_kernel<<<dim3(S_MEM / 1024, LT / 64, BB * NH), 256, 0, stream>>>(
            sc, kv + 256, S_MEM * 512, 512, obuf, S_MEM, 1024);
        gemm_bias_kernel<<<dim3(D / 64, NTOK / 64), 256, 0, stream>>>(
            obuf, caw + 3 * D * D, cab + 3 * D, t2b, NTOK, D, D, 0);
        ln_kernel<<<NTOK, D, 0, stream>>>(tgtb, t2b, lg + D, lb + D);

        // ---- FFN ----
        gemm_bias_kernel<<<dim3(DFF / 64, NTOK / 64), 256, 0, stream>>>(
            tgtb, ff_w1 + (size_t)i * DFF * D, ff_b1 + (size_t)i * DFF, hbuf, NTOK, DFF, D, 1);
        gemm_bias_kernel<<<dim3(D / 64, NTOK / 64), 256, 0, stream>>>(
            hbuf, ff_w2 + (size_t)i * D * DFF, ff_b2 + (size_t)i * D, t2b, NTOK, D, DFF, 0);
        ln_kernel<<<NTOK, D, 0, stream>>>(tgtb, t2b, lg + 2 * D, lb + 2 * D);
    }

    gemm_bias_kernel<<<dim3((VOCAB + 63) / 64, NTOK / 64), 256, 0, stream>>>(
        tgtb, out_w, out_b, out, NTOK, VOCAB, D, 0);
}

// Round 7
// 3593.913 us; speedup vs baseline: 1.4712x; 1.4712x over previous
//
#include <hip/hip_runtime.h>
#include <hip/hip_bf16.h>

#define D 256
#define NH 4
#define HD 64
#define NL 8
#define DFF 1024
#define VOCAB 100
#define LT 256
#define BB 2
#define FH 32
#define FW 256
#define S_MEM (FH*FW)        // 8192
#define NTOK (LT*BB)         // 512 token rows
#define MEMROWS (BB*S_MEM)   // 16384 memory rows
#define EPS 1e-5f

typedef __attribute__((ext_vector_type(8))) short s8v;
typedef __attribute__((ext_vector_type(4))) float f4v;

__device__ __forceinline__ short f2bf(float x) {
    union { float f; unsigned u; } v; v.f = x;
    unsigned r = v.u + 0x7FFF + ((v.u >> 16) & 1);   // RNE
    return (short)(r >> 16);
}

// ---------------------------------------------------------------------------
// mem = features + PE2D, transposed (B,C,H,W) -> [B][S=H*W][C], bf16 out
// ---------------------------------------------------------------------------
__global__ __launch_bounds__(256) void build_mem_kernel(const float* __restrict__ f,
                                                        short* __restrict__ memb)
{
    __shared__ float tile[32][33];
    int wt = blockIdx.x * 32, ct = blockIdx.y * 32;
    int b = blockIdx.z >> 5, h = blockIdx.z & 31;
    int tx = threadIdx.x, ty = threadIdx.y;  // 32 x 8
#pragma unroll
    for (int p = 0; p < 4; ++p) {
        int c = ty + p * 8;
        tile[c][tx] = f[(((size_t)(b * D + ct + c)) * FH + h) * FW + wt + tx];
    }
    __syncthreads();
#pragma unroll
    for (int p = 0; p < 4; ++p) {
        int wl = ty + p * 8;
        int c = ct + tx;
        int w = wt + wl;
        int j2 = (c & 127) & ~1;                // 2*j
        float dv = expf(-((float)j2 * (1.f / 256.f)) * 9.210340371976184f);
        float pos = (c < 128) ? (float)h : (float)w;
        float ang = pos * dv;
        float pe = (c & 1) ? cosf(ang) : sinf(ang);
        memb[((size_t)b * S_MEM + (size_t)h * FW + w) * D + c] = f2bf(tile[tx][wl] + pe);
    }
}

// ---------------------------------------------------------------------------
// tgt = emb[tokens] + PE1D, layout [L][B][D]
// ---------------------------------------------------------------------------
__global__ __launch_bounds__(256) void embed_kernel(const int* __restrict__ tokens,
                                                    const float* __restrict__ emb,
                                                    float* __restrict__ tgt)
{
    int r = blockIdx.x;
    int d = threadIdx.x;
    int l = r >> 1;
    int tok = tokens[r];
    int j2 = d & ~1;
    float dv = expf(-((float)j2 * (1.f / 256.f)) * 9.210340371976184f);
    float ang = (float)l * dv;
    float pe = (d & 1) ? cosf(ang) : sinf(ang);
    tgt[(size_t)r * D + d] = emb[(size_t)tok * D + d] + pe;
}

// ---------------------------------------------------------------------------
// fp32 -> bf16 conversion, n % 8 == 0
// ---------------------------------------------------------------------------
__global__ __launch_bounds__(256) void cvt_kernel(const float* __restrict__ in,
                                                  short* __restrict__ out, int n)
{
    int i = (blockIdx.x * 256 + threadIdx.x) * 8;
    if (i >= n) return;
    float4 a = *(const float4*)&in[i];
    float4 b = *(const float4*)&in[i + 4];
    s8v v;
    v[0] = f2bf(a.x); v[1] = f2bf(a.y); v[2] = f2bf(a.z); v[3] = f2bf(a.w);
    v[4] = f2bf(b.x); v[5] = f2bf(b.y); v[6] = f2bf(b.z); v[7] = f2bf(b.w);
    *(s8v*)&out[i] = v;
}

// ---------------------------------------------------------------------------
// fp32 GEMM (self-attn/FFN/projections):
// C[M,N] = A[M,K] @ W[N,K]^T + bias[N] (optional ReLU)
// ---------------------------------------------------------------------------
#define GKT 32
__global__ __launch_bounds__(256) void gemm_bias_kernel(const float* __restrict__ A,
                                                        const float* __restrict__ W,
                                                        const float* __restrict__ bias,
                                                        float* __restrict__ C,
                                                        int M, int N, int K, int relu)
{
    __shared__ float As[64][GKT + 4];
    __shared__ float Bs[64][GKT + 4];
    const int tid = threadIdx.x;
    const int tx = tid & 15, ty = tid >> 4;
    const int m0 = blockIdx.y * 64, n0 = blockIdx.x * 64;
    const int lcol = tid & 31;
    const int lrow = tid >> 5;
    float acc[4][4] = {};
    for (int k0 = 0; k0 < K; k0 += GKT) {
#pragma unroll
        for (int p = 0; p < 8; ++p) {
            int r = lrow + p * 8;
            As[r][lcol] = A[(size_t)(m0 + r) * K + k0 + lcol];
            int n = n0 + r;
            Bs[r][lcol] = (n < N) ? W[(size_t)n * K + k0 + lcol] : 0.f;
        }
        __syncthreads();
#pragma unroll
        for (int k4 = 0; k4 < GKT / 4; ++k4) {
            float4 av[4], bv[4];
#pragma unroll
            for (int i = 0; i < 4; ++i) av[i] = *(const float4*)&As[ty + 16 * i][k4 * 4];
#pragma unroll
            for (int j = 0; j < 4; ++j) bv[j] = *(const float4*)&Bs[tx + 16 * j][k4 * 4];
#pragma unroll
            for (int i = 0; i < 4; ++i)
#pragma unroll
                for (int j = 0; j < 4; ++j)
                    acc[i][j] += av[i].x * bv[j].x + av[i].y * bv[j].y +
                                 av[i].z * bv[j].z + av[i].w * bv[j].w;
        }
        __syncthreads();
    }
#pragma unroll
    for (int i = 0; i < 4; ++i) {
        int m = m0 + ty + 16 * i;
#pragma unroll
        for (int j = 0; j < 4; ++j) {
            int n = n0 + tx + 16 * j;
            if (n < N) {
                float v = acc[i][j] + bias[n];
                if (relu) v = fmaxf(v, 0.f);
                C[(size_t)m * N + n] = v;
            }
        }
    }
}

// ---------------------------------------------------------------------------
// bf16 MFMA GEMM: C_bf16[M,N] = A_bf16[M,K] @ W_bf16[N,K]^T + bias[N]
// 128x128 tile, 4 waves 2x2, BK=32. M,N % 128 == 0, K % 32 == 0.
// A-frag: row=lane&15, k=(lane>>4)*8+j ; C/D: col=lane&15, row=(lane>>4)*4+q
// ---------------------------------------------------------------------------
__global__ __launch_bounds__(256) void gemm_bf16_kernel(const short* __restrict__ A,
                                                        const short* __restrict__ W,
                                                        const float* __restrict__ bias,
                                                        short* __restrict__ C,
                                                        int M, int N, int K)
{
    __shared__ short As[128][40];
    __shared__ short Bs[128][40];
    const int tid = threadIdx.x;
    const int lane = tid & 63, wave = tid >> 6;
    const int wm = wave >> 1, wn = wave & 1;
    const int m0 = blockIdx.y * 128, n0 = blockIdx.x * 128;
    f4v acc[4][4] = {};
    for (int k0 = 0; k0 < K; k0 += 32) {
#pragma unroll
        for (int p = 0; p < 2; ++p) {
            int ci = tid + p * 256;
            int r = ci >> 2, c = (ci & 3) * 8;
            *(s8v*)&As[r][c] = *(const s8v*)&A[(size_t)(m0 + r) * K + k0 + c];
            *(s8v*)&Bs[r][c] = *(const s8v*)&W[(size_t)(n0 + r) * K + k0 + c];
        }
        __syncthreads();
        s8v af[4], bfr[4];
#pragma unroll
        for (int i = 0; i < 4; ++i)
            af[i] = *(const s8v*)&As[wm * 64 + i * 16 + (lane & 15)][(lane >> 4) * 8];
#pragma unroll
        for (int j = 0; j < 4; ++j)
            bfr[j] = *(const s8v*)&Bs[wn * 64 + j * 16 + (lane & 15)][(lane >> 4) * 8];
#pragma unroll
        for (int i = 0; i < 4; ++i)
#pragma unroll
            for (int j = 0; j < 4; ++j)
                acc[i][j] = __builtin_amdgcn_mfma_f32_16x16x32_bf16(af[i], bfr[j], acc[i][j], 0, 0, 0);
        __syncthreads();
    }
#pragma unroll
    for (int i = 0; i < 4; ++i)
#pragma unroll
        for (int j = 0; j < 4; ++j) {
            int col = n0 + wn * 64 + j * 16 + (lane & 15);
            float bv = bias[col];
#pragma unroll
            for (int q = 0; q < 4; ++q) {
                int row = m0 + wm * 64 + i * 16 + (lane >> 4) * 4 + q;
                C[(size_t)row * N + col] = f2bf(acc[i][j][q] + bv);
            }
        }
}

// ---------------------------------------------------------------------------
// cross scores (bf16 MFMA): Sc[bh][l][s] = scale * dot64(q[l], k[s]), fp32 out
// 128x128 tile, K=64 (single stage). grid (S/128, L/128, 8)
// ---------------------------------------------------------------------------
__global__ __launch_bounds__(256) void scores_bf16_kernel(const short* __restrict__ Q,
                                                          const short* __restrict__ kvb,
                                                          float* __restrict__ Sc,
                                                          float scale)
{
    __shared__ short Qs[128][72];
    __shared__ short Ks[128][72];
    const int tid = threadIdx.x;
    const int lane = tid & 63, wave = tid >> 6;
    const int wm = wave >> 1, wn = wave & 1;
    const int bh = blockIdx.z, b = bh >> 2, h = bh & 3;
    const int l0 = blockIdx.y * 128, s0 = blockIdx.x * 128;
#pragma unroll
    for (int p = 0; p < 4; ++p) {
        int ci = tid + p * 256;
        int r = ci >> 3, c = (ci & 7) * 8;
        *(s8v*)&Qs[r][c] = *(const s8v*)&Q[((size_t)(l0 + r) * BB + b) * D + h * HD + c];
        *(s8v*)&Ks[r][c] = *(const s8v*)&kvb[((size_t)b * S_MEM + s0 + r) * 512 + h * HD + c];
    }
    __syncthreads();
    f4v acc[4][4] = {};
#pragma unroll
    for (int kk = 0; kk < 2; ++kk) {
        s8v af[4], bfr[4];
#pragma unroll
        for (int i = 0; i < 4; ++i)
            af[i] = *(const s8v*)&Qs[wm * 64 + i * 16 + (lane & 15)][kk * 32 + (lane >> 4) * 8];
#pragma unroll
        for (int j = 0; j < 4; ++j)
            bfr[j] = *(const s8v*)&Ks[wn * 64 + j * 16 + (lane & 15)][kk * 32 + (lane >> 4) * 8];
#pragma unroll
        for (int i = 0; i < 4; ++i)
#pragma unroll
            for (int j = 0; j < 4; ++j)
                acc[i][j] = __builtin_amdgcn_mfma_f32_16x16x32_bf16(af[i], bfr[j], acc[i][j], 0, 0, 0);
    }
#pragma unroll
    for (int i = 0; i < 4; ++i)
#pragma unroll
        for (int q = 0; q < 4; ++q) {
            int l = l0 + wm * 64 + i * 16 + (lane >> 4) * 4 + q;
            size_t rowoff = ((size_t)bh * LT + l) * S_MEM;
#pragma unroll
            for (int j = 0; j < 4; ++j) {
                int s = s0 + wn * 64 + j * 16 + (lane & 15);
                Sc[rowoff + s] = acc[i][j][q] * scale;
            }
        }
}

// ---------------------------------------------------------------------------
// V transpose: Vt[bh][d][s] <- kv[b*S+s][256 + h*64 + d]
// ---------------------------------------------------------------------------
__global__ __launch_bounds__(256) void vtrans_kernel(const short* __restrict__ kvb,
                                                     short* __restrict__ Vt)
{
    __shared__ short t[64][72];
    int s0 = blockIdx.x * 64, bh = blockIdx.y, b = bh >> 2, h = bh & 3;
    const short* src = kvb + ((size_t)b * S_MEM) * 512 + 256 + h * HD;
    int tid = threadIdx.x;
#pragma unroll
    for (int p = 0; p < 2; ++p) {
        int r = (tid >> 3) + p * 32;
        int c = (tid & 7) * 8;
        *(s8v*)&t[r][c] = *(const s8v*)&src[(size_t)(s0 + r) * 512 + c];
    }
    __syncthreads();
    int d = tid >> 2, s1 = (tid & 3) * 16;
    short v[16];
#pragma unroll
    for (int j = 0; j < 16; ++j) v[j] = t[s1 + j][d];
    *(s8v*)&Vt[((size_t)bh * HD + d) * S_MEM + s0 + s1] = *(s8v*)&v[0];
    *(s8v*)&Vt[((size_t)bh * HD + d) * S_MEM + s0 + s1 + 8] = *(s8v*)&v[8];
}

// ---------------------------------------------------------------------------
// PV (bf16 MFMA, split-K atomics): O[l,b,h*64+d] += sum_s P[bh][l][s]*Vt[bh][d][s]
// P is fp32 (normalized in place by softmax); converted to bf16 during staging.
// block tile 128(l) x 64(d), 4 waves stacked in l; chunk SK=512 of s.
// ---------------------------------------------------------------------------
__global__ __launch_bounds__(256) void pv_bf16_kernel(const float* __restrict__ P,
                                                      const short* __restrict__ Vt,
                                                      float* __restrict__ O)
{
    __shared__ short Ps[128][40];
    __shared__ short Vs[64][40];
    const int tid = threadIdx.x;
    const int lane = tid & 63, wm = tid >> 6;
    const int bh = blockIdx.z, b = bh >> 2, h = bh & 3;
    const int l0 = blockIdx.y * 128;
    const int sBeg = blockIdx.x * 512;
    f4v acc[2][4] = {};
    for (int ks = 0; ks < 512; ks += 32) {
#pragma unroll
        for (int p = 0; p < 2; ++p) {
            int ci = tid + p * 256;
            int r = ci >> 2, c = (ci & 3) * 8;
            const float* src = &P[((size_t)bh * LT + l0 + r) * S_MEM + sBeg + ks + c];
            float4 a = *(const float4*)src;
            float4 bq = *(const float4*)(src + 4);
            s8v v;
            v[0] = f2bf(a.x); v[1] = f2bf(a.y); v[2] = f2bf(a.z); v[3] = f2bf(a.w);
            v[4] = f2bf(bq.x); v[5] = f2bf(bq.y); v[6] = f2bf(bq.z); v[7] = f2bf(bq.w);
            *(s8v*)&Ps[r][c] = v;
        }
        {
            int r = tid >> 2, c = (tid & 3) * 8;
            *(s8v*)&Vs[r][c] = *(const s8v*)&Vt[((size_t)bh * HD + r) * S_MEM + sBeg + ks + c];
        }
        __syncthreads();
        s8v af[2], bfr[4];
#pragma unroll
        for (int i = 0; i < 2; ++i)
            af[i] = *(const s8v*)&Ps[wm * 32 + i * 16 + (lane & 15)][(lane >> 4) * 8];
#pragma unroll
        for (int j = 0; j < 4; ++j)
            bfr[j] = *(const s8v*)&Vs[j * 16 + (lane & 15)][(lane >> 4) * 8];
#pragma unroll
        for (int i = 0; i < 2; ++i)
#pragma unroll
            for (int j = 0; j < 4; ++j)
                acc[i][j] = __builtin_amdgcn_mfma_f32_16x16x32_bf16(af[i], bfr[j], acc[i][j], 0, 0, 0);
        __syncthreads();
    }
#pragma unroll
    for (int i = 0; i < 2; ++i)
#pragma unroll
        for (int q = 0; q < 4; ++q) {
            int l = l0 + wm * 32 + i * 16 + (lane >> 4) * 4 + q;
#pragma unroll
            for (int j = 0; j < 4; ++j) {
                int d = j * 16 + (lane & 15);
                atomicAdd(&O[((size_t)l * BB + b) * D + h * HD + d], acc[i][j][q]);
            }
        }
}

// ---------------------------------------------------------------------------
// fp32 self-attn scores
// ---------------------------------------------------------------------------
__global__ __launch_bounds__(256) void attn_scores_kernel(const float* __restrict__ Q,
                                                          int qStrideB, int qStrideL,
                                                          const float* __restrict__ Kp,
                                                          int kStrideB, int kStrideS,
                                                          float* __restrict__ Sc,
                                                          int Sk, float scale)
{
    __shared__ float Qs[64][68];
    __shared__ float Ks[64][68];
    int bh = blockIdx.z, b = bh >> 2, h = bh & 3;
    int l0 = blockIdx.y * 64, s0 = blockIdx.x * 64;
    const float* Qb = Q + (size_t)b * qStrideB + h * HD;
    const float* Kb = Kp + (size_t)b * kStrideB + h * HD;
    int tid = threadIdx.x;
    int lcol = tid & 63, lrow = tid >> 6;
#pragma unroll
    for (int p = 0; p < 16; ++p) {
        int r = lrow + p * 4;
        Qs[r][lcol] = Qb[(size_t)(l0 + r) * qStrideL + lcol];
        Ks[r][lcol] = Kb[(size_t)(s0 + r) * kStrideS + lcol];
    }
    __syncthreads();
    int tx = tid & 15, ty = tid >> 4;
    float acc[4][4] = {};
#pragma unroll
    for (int k4 = 0; k4 < 16; ++k4) {
        float4 av[4], bv[4];
#pragma unroll
        for (int i = 0; i < 4; ++i) av[i] = *(const float4*)&Qs[ty + 16 * i][k4 * 4];
#pragma unroll
        for (int j = 0; j < 4; ++j) bv[j] = *(const float4*)&Ks[tx + 16 * j][k4 * 4];
#pragma unroll
        for (int i = 0; i < 4; ++i)
#pragma unroll
            for (int j = 0; j < 4; ++j)
                acc[i][j] += av[i].x * bv[j].x + av[i].y * bv[j].y +
                             av[i].z * bv[j].z + av[i].w * bv[j].w;
    }
#pragma unroll
    for (int i = 0; i < 4; ++i) {
        size_t rowoff = ((size_t)bh * LT + l0 + ty + 16 * i) * Sk + s0;
#pragma unroll
        for (int j = 0; j < 4; ++j)
            Sc[rowoff + tx + 16 * j] = acc[i][j] * scale;
    }
}

// ---------------------------------------------------------------------------
// row softmax fp32 in place. NIT=Sk/256. causal masks s>l (writes 0 there).
// ---------------------------------------------------------------------------
template <int NIT>
__global__ __launch_bounds__(256) void softmax_kernel(float* __restrict__ Sc, int Sk, int causal)
{
    int l = blockIdx.x, bh = blockIdx.y;
    float* row = Sc + ((size_t)bh * LT + l) * Sk;
    int valid = causal ? (l + 1) : Sk;
    int tid = threadIdx.x;
    float vals[NIT];
    float m = -3.0e38f;
#pragma unroll
    for (int i = 0; i < NIT; ++i) {
        int idx = tid + i * 256;
        float v = (idx < valid) ? row[idx] : -3.0e38f;
        vals[i] = v;
        m = fmaxf(m, v);
    }
#pragma unroll
    for (int off = 32; off; off >>= 1) m = fmaxf(m, __shfl_xor(m, off));
    __shared__ float smax[4];
    __shared__ float ssum[4];
    int lane = tid & 63, w = tid >> 6;
    if (lane == 0) smax[w] = m;
    __syncthreads();
    m = fmaxf(fmaxf(smax[0], smax[1]), fmaxf(smax[2], smax[3]));
    float s = 0.f;
#pragma unroll
    for (int i = 0; i < NIT; ++i) {
        int idx = tid + i * 256;
        float e = (idx < valid) ? __expf(vals[i] - m) : 0.f;
        vals[i] = e;
        s += e;
    }
#pragma unroll
    for (int off = 32; off; off >>= 1) s += __shfl_xor(s, off);
    if (lane == 0) ssum[w] = s;
    __syncthreads();
    s = ssum[0] + ssum[1] + ssum[2] + ssum[3];
    float inv = 1.f / s;
#pragma unroll
    for (int i = 0; i < NIT; ++i) {
        int idx = tid + i * 256;
        row[idx] = vals[i] * inv;
    }
}

// ---------------------------------------------------------------------------
// fp32 self-attn PV
// ---------------------------------------------------------------------------
__global__ __launch_bounds__(256) void attn_pv_kernel(const float* __restrict__ P,
                                                      const float* __restrict__ V,
                                                      int vStrideB, int vStrideS,
                                                      float* __restrict__ O,
                                                      int Sk, int chunk)
{
    __shared__ float Ps[64][20];
    __shared__ float Vs[16][68];
    int bh = blockIdx.z, b = bh >> 2, h = bh & 3;
    int l0 = blockIdx.y * 64;
    int sBeg = blockIdx.x * chunk;
    const float* Pb = P + ((size_t)bh * LT + l0) * Sk;
    const float* Vb = V + (size_t)b * vStrideB + h * HD;
    int tid = threadIdx.x;
    int tx = tid & 15, ty = tid >> 4;
    float acc[4][4] = {};
    for (int s0 = sBeg; s0 < sBeg + chunk; s0 += 16) {
        {
            int lc = tid & 15, lr = tid >> 4;
#pragma unroll
            for (int p = 0; p < 4; ++p) {
                int r = lr + p * 16;
                Ps[r][lc] = Pb[(size_t)r * Sk + s0 + lc];
            }
            int vd = tid & 63, vs = tid >> 6;
#pragma unroll
            for (int p = 0; p < 4; ++p) {
                int s = vs + p * 4;
                Vs[s][vd] = Vb[(size_t)(s0 + s) * vStrideS + vd];
            }
        }
        __syncthreads();
#pragma unroll
        for (int k4 = 0; k4 < 4; ++k4) {
            float pa[4][4];
#pragma unroll
            for (int i = 0; i < 4; ++i) {
                float4 t = *(const float4*)&Ps[ty + 16 * i][k4 * 4];
                pa[i][0] = t.x; pa[i][1] = t.y; pa[i][2] = t.z; pa[i][3] = t.w;
            }
#pragma unroll
            for (int kk = 0; kk < 4; ++kk) {
                float bj[4];
#pragma unroll
                for (int j = 0; j < 4; ++j) bj[j] = Vs[k4 * 4 + kk][tx + 16 * j];
#pragma unroll
                for (int i = 0; i < 4; ++i)
#pragma unroll
                    for (int j = 0; j < 4; ++j) acc[i][j] += pa[i][kk] * bj[j];
            }
        }
        __syncthreads();
    }
#pragma unroll
    for (int i = 0; i < 4; ++i) {
        int l = l0 + ty + 16 * i;
#pragma unroll
        for (int j = 0; j < 4; ++j)
            atomicAdd(&O[((size_t)l * BB + b) * D + h * HD + tx + 16 * j], acc[i][j]);
    }
}

// ---------------------------------------------------------------------------
// tgt = LayerNorm(tgt + t2) * g + beta
// ---------------------------------------------------------------------------
__global__ __launch_bounds__(256) void ln_kernel(float* __restrict__ tgt,
                                                 const float* __restrict__ t2,
                                                 const float* __restrict__ g,
                                                 const float* __restrict__ beta)
{
    int r = blockIdx.x, d = threadIdx.x;
    float x = tgt[(size_t)r * D + d] + t2[(size_t)r * D + d];
    float v1 = x, v2 = x * x;
#pragma unroll
    for (int off = 32; off; off >>= 1) {
        v1 += __shfl_xor(v1, off);
        v2 += __shfl_xor(v2, off);
    }
    __shared__ float s1[4], s2[4];
    int lane = d & 63, w = d >> 6;
    if (lane == 0) { s1[w] = v1; s2[w] = v2; }
    __syncthreads();
    float sum = s1[0] + s1[1] + s1[2] + s1[3];
    float sums = s2[0] + s2[1] + s2[2] + s2[3];
    float mean = sum * (1.f / 256.f);
    float var = sums * (1.f / 256.f) - mean * mean;
    tgt[(size_t)r * D + d] = (x - mean) * rsqrtf(var + EPS) * g[d] + beta[d];
}

// ---------------------------------------------------------------------------
extern "C" void kernel_launch(void* const* d_in, const int* in_sizes, int n_in,
                              void* d_out, int out_size, void* d_ws, size_t ws_size,
                              hipStream_t stream)
{
    (void)in_sizes; (void)n_in; (void)out_size; (void)ws_size;
    const int*   tokens   = (const int*)d_in[0];
    const float* features = (const float*)d_in[1];
    const float* emb      = (const float*)d_in[2];
    const float* sa_w     = (const float*)d_in[3];
    const float* sa_b     = (const float*)d_in[4];
    const float* ca_w     = (const float*)d_in[5];
    const float* ca_b     = (const float*)d_in[6];
    const float* ln_g     = (const float*)d_in[7];
    const float* ln_b     = (const float*)d_in[8];
    const float* ff_w1    = (const float*)d_in[9];
    const float* ff_b1    = (const float*)d_in[10];
    const float* ff_w2    = (const float*)d_in[11];
    const float* ff_b2    = (const float*)d_in[12];
    const float* out_w    = (const float*)d_in[13];
    const float* out_b    = (const float*)d_in[14];
    float* out = (float*)d_out;

    // workspace layout (~109 MB total; Round-1 proved >= 123 MB available)
    float* ws = (float*)d_ws;
    float* sc    = ws;                         // 16,777,216 f (64MB) scores/P
    float* tgtb  = sc + 16777216;              // 131,072 f
    float* qkv   = tgtb + 131072;              // 393,216 f
    float* qc    = qkv + 393216;               // 131,072 f
    float* obuf  = qc + 131072;                // 131,072 f
    float* t2b   = obuf + 131072;              // 131,072 f
    float* hbuf  = t2b + 131072;               // 524,288 f
    short* membb = (short*)(hbuf + 524288);    // 4,194,304 s (8MB)
    short* kvb   = membb + 4194304;            // 8,388,608 s (16MB)
    short* vtb   = kvb + 8388608;              // 4,194,304 s (8MB)
    short* qb    = vtb + 4194304;              // 131,072 s
    short* kvwb  = qb + 131072;                // 8 * 131,072 s (2MB) kv weights bf16

    const float scale = 0.125f;  // hd^-0.5

    build_mem_kernel<<<dim3(FW / 32, D / 32, BB * FH), dim3(32, 8), 0, stream>>>(features, membb);
    embed_kernel<<<NTOK, D, 0, stream>>>(tokens, emb, tgtb);
    for (int i = 0; i < NL; ++i)   // convert K/V weight blocks (512x256 each) to bf16
        cvt_kernel<<<(2 * D * D) / (256 * 8), 256, 0, stream>>>(
            ca_w + (size_t)i * 4 * D * D + D * D, kvwb + (size_t)i * 2 * D * D, 2 * D * D);

    for (int i = 0; i < NL; ++i) {
        const float* saw = sa_w + (size_t)i * 4 * D * D;
        const float* sab = sa_b + (size_t)i * 4 * D;
        const float* caw = ca_w + (size_t)i * 4 * D * D;
        const float* cab = ca_b + (size_t)i * 4 * D;
        const short* kvw = kvwb + (size_t)i * 2 * D * D;
        const float* lg  = ln_g + (size_t)i * 3 * D;
        const float* lb  = ln_b + (size_t)i * 3 * D;

        // ---- self attention (causal, fp32) ----
        gemm_bias_kernel<<<dim3(768 / 64, NTOK / 64), 256, 0, stream>>>(
            tgtb, saw, sab, qkv, NTOK, 768, D, 0);
        attn_scores_kernel<<<dim3(LT / 64, LT / 64, BB * NH), 256, 0, stream>>>(
            qkv, 768, 2 * 768, qkv + 256, 768, 2 * 768, sc, LT, scale);
        softmax_kernel<1><<<dim3(LT, BB * NH), 256, 0, stream>>>(sc, LT, 1);
        hipMemsetAsync(obuf, 0, (size_t)NTOK * D * sizeof(float), stream);
        attn_pv_kernel<<<dim3(1, LT / 64, BB * NH), 256, 0, stream>>>(
            sc, qkv + 512, 768, 2 * 768, obuf, LT, LT);
        gemm_bias_kernel<<<dim3(D / 64, NTOK / 64), 256, 0, stream>>>(
            obuf, saw + 3 * D * D, sab + 3 * D, t2b, NTOK, D, D, 0);
        ln_kernel<<<NTOK, D, 0, stream>>>(tgtb, t2b, lg, lb);

        // ---- cross attention (bf16 MFMA core) ----
        gemm_bias_kernel<<<dim3(D / 64, NTOK / 64), 256, 0, stream>>>(
            tgtb, caw, cab, qc, NTOK, D, D, 0);
        cvt_kernel<<<(NTOK * D) / (256 * 8), 256, 0, stream>>>(qc, qb, NTOK * D);
        gemm_bf16_kernel<<<dim3(512 / 128, MEMROWS / 128), 256, 0, stream>>>(
            membb, kvw, cab + D, kvb, MEMROWS, 512, D);
        vtrans_kernel<<<dim3(S_MEM / 64, BB * NH), 256, 0, stream>>>(kvb, vtb);
        scores_bf16_kernel<<<dim3(S_MEM / 128, LT / 128, BB * NH), 256, 0, stream>>>(
            qb, kvb, sc, scale);
        softmax_kernel<32><<<dim3(LT, BB * NH), 256, 0, stream>>>(sc, S_MEM, 0);
        hipMemsetAsync(obuf, 0, (size_t)NTOK * D * sizeof(float), stream);
        pv_bf16_kernel<<<dim3(S_MEM / 512, LT / 128, BB * NH), 256, 0, stream>>>(
            sc, vtb, obuf);
        gemm_bias_kernel<<<dim3(D / 64, NTOK / 64), 256, 0, stream>>>(
            obuf, caw + 3 * D * D, cab + 3 * D, t2b, NTOK, D, D, 0);
        ln_kernel<<<NTOK, D, 0, stream>>>(tgtb, t2b, lg + D, lb + D);

        // ---- FFN (fp32) ----
        gemm_bias_kernel<<<dim3(DFF / 64, NTOK / 64), 256, 0, stream>>>(
            tgtb, ff_w1 + (size_t)i * DFF * D, ff_b1 + (size_t)i * DFF, hbuf, NTOK, DFF, D, 1);
        gemm_bias_kernel<<<dim3(D / 64, NTOK / 64), 256, 0, stream>>>(
            hbuf, ff_w2 + (size_t)i * D * DFF, ff_b2 + (size_t)i * D, t2b, NTOK, D, DFF, 0);
        ln_kernel<<<NTOK, D, 0, stream>>>(tgtb, t2b, lg + 2 * D, lb + 2 * D);
    }

    gemm_bias_kernel<<<dim3((VOCAB + 63) / 64, NTOK / 64), 256, 0, stream>>>(
        tgtb, out_w, out_b, out, NTOK, VOCAB, D, 0);
}

// Round 9
// 1294.521 us; speedup vs baseline: 4.0844x; 2.7762x over previous
//
#include <hip/hip_runtime.h>
#include <hip/hip_bf16.h>

#define D 256
#define NH 4
#define HD 64
#define NL 8
#define DFF 1024
#define VOCAB 100
#define LT 256
#define BB 2
#define FH 32
#define FW 256
#define S_MEM (FH*FW)        // 8192
#define NTOK (LT*BB)         // 512 token rows
#define MEMROWS (BB*S_MEM)   // 16384 memory rows
#define EPS 1e-5f

typedef __attribute__((ext_vector_type(8))) short s8v;
typedef __attribute__((ext_vector_type(4))) float f4v;

__device__ __forceinline__ short f2bf(float x) {
    union { float f; unsigned u; } v; v.f = x;
    unsigned r = v.u + 0x7FFF + ((v.u >> 16) & 1);   // RNE
    return (short)(r >> 16);
}

// ---------------------------------------------------------------------------
// mem = features + PE2D, transposed (B,C,H,W) -> [B][S=H*W][C], bf16 out
// ---------------------------------------------------------------------------
__global__ __launch_bounds__(256) void build_mem_kernel(const float* __restrict__ f,
                                                        short* __restrict__ memb)
{
    __shared__ float tile[32][33];
    int wt = blockIdx.x * 32, ct = blockIdx.y * 32;
    int b = blockIdx.z >> 5, h = blockIdx.z & 31;
    int tx = threadIdx.x, ty = threadIdx.y;  // 32 x 8
#pragma unroll
    for (int p = 0; p < 4; ++p) {
        int c = ty + p * 8;
        tile[c][tx] = f[(((size_t)(b * D + ct + c)) * FH + h) * FW + wt + tx];
    }
    __syncthreads();
#pragma unroll
    for (int p = 0; p < 4; ++p) {
        int wl = ty + p * 8;
        int c = ct + tx;
        int w = wt + wl;
        int j2 = (c & 127) & ~1;                // 2*j
        float dv = expf(-((float)j2 * (1.f / 256.f)) * 9.210340371976184f);
        float pos = (c < 128) ? (float)h : (float)w;
        float ang = pos * dv;
        float pe = (c & 1) ? cosf(ang) : sinf(ang);
        memb[((size_t)b * S_MEM + (size_t)h * FW + w) * D + c] = f2bf(tile[tx][wl] + pe);
    }
}

// ---------------------------------------------------------------------------
// tgt = emb[tokens] + PE1D (fp32 + bf16 shadow)
// ---------------------------------------------------------------------------
__global__ __launch_bounds__(256) void embed_kernel(const int* __restrict__ tokens,
                                                    const float* __restrict__ emb,
                                                    float* __restrict__ tgt,
                                                    short* __restrict__ tgt_bf)
{
    int r = blockIdx.x;
    int d = threadIdx.x;
    int l = r >> 1;
    int tok = tokens[r];
    int j2 = d & ~1;
    float dv = expf(-((float)j2 * (1.f / 256.f)) * 9.210340371976184f);
    float ang = (float)l * dv;
    float pe = (d & 1) ? cosf(ang) : sinf(ang);
    float y = emb[(size_t)tok * D + d] + pe;
    tgt[(size_t)r * D + d] = y;
    tgt_bf[(size_t)r * D + d] = f2bf(y);
}

// ---------------------------------------------------------------------------
// fp32 -> bf16 conversion, n % 8 == 0 (used for cross K/V weights)
// ---------------------------------------------------------------------------
__global__ __launch_bounds__(256) void cvt_kernel(const float* __restrict__ in,
                                                  short* __restrict__ out, int n)
{
    int i = (blockIdx.x * 256 + threadIdx.x) * 8;
    if (i >= n) return;
    float4 a = *(const float4*)&in[i];
    float4 b = *(const float4*)&in[i + 4];
    s8v v;
    v[0] = f2bf(a.x); v[1] = f2bf(a.y); v[2] = f2bf(a.z); v[3] = f2bf(a.w);
    v[4] = f2bf(b.x); v[5] = f2bf(b.y); v[6] = f2bf(b.z); v[7] = f2bf(b.w);
    *(s8v*)&out[i] = v;
}

// ---------------------------------------------------------------------------
// Single-stage bf16 MFMA GEMM for small/latency-bound shapes.
// C[M,N] (+=) A[M,K-chunk] @ W[N,K-chunk]^T (+ bias)
// 64x64 tile, 4 waves (2x2 of 32x32), K-chunk = 256 staged once (no K-loop).
// ABF: A is bf16 (else fp32, cvt in staging). W always fp32 (cvt in staging).
// SPLIT: atomicAdd fp32, no bias (grid.z = K/256). OBF: bf16 output.
// M%64==0, K%256==0; N guarded (for VOCAB=100).
// ---------------------------------------------------------------------------
template <int ABF, int RELU, int SPLIT, int OBF>
__global__ __launch_bounds__(256) void gemm_small_kernel(const void* __restrict__ Ap,
                                                         const float* __restrict__ W,
                                                         const float* __restrict__ bias,
                                                         void* __restrict__ Cp,
                                                         int M, int N, int K)
{
    __shared__ short As[64][264];
    __shared__ short Bs[64][264];
    const int tid = threadIdx.x;
    const int lane = tid & 63, wave = tid >> 6;
    const int wm = wave >> 1, wn = wave & 1;
    const int m0 = blockIdx.y * 64, n0 = blockIdx.x * 64;
    const int k0 = blockIdx.z * 256;
    // stage A (64 x 256)
    if (ABF) {
        const short* A = (const short*)Ap;
#pragma unroll
        for (int p = 0; p < 8; ++p) {
            int idx = p * 2048 + tid * 8;
            int r = idx >> 8, c = idx & 255;
            *(s8v*)&As[r][c] = *(const s8v*)&A[(size_t)(m0 + r) * K + k0 + c];
        }
    } else {
        const float* A = (const float*)Ap;
#pragma unroll
        for (int p = 0; p < 8; ++p) {
            int idx = p * 2048 + tid * 8;
            int r = idx >> 8, c = idx & 255;
            const float* src = &A[(size_t)(m0 + r) * K + k0 + c];
            float4 a = *(const float4*)src;
            float4 b = *(const float4*)(src + 4);
            s8v v;
            v[0] = f2bf(a.x); v[1] = f2bf(a.y); v[2] = f2bf(a.z); v[3] = f2bf(a.w);
            v[4] = f2bf(b.x); v[5] = f2bf(b.y); v[6] = f2bf(b.z); v[7] = f2bf(b.w);
            *(s8v*)&As[r][c] = v;
        }
    }
    // stage W (64 x 256), fp32 -> bf16, rows >= N zeroed
#pragma unroll
    for (int p = 0; p < 8; ++p) {
        int idx = p * 2048 + tid * 8;
        int r = idx >> 8, c = idx & 255;
        s8v v;
        if (n0 + r < N) {
            const float* src = &W[(size_t)(n0 + r) * K + k0 + c];
            float4 a = *(const float4*)src;
            float4 b = *(const float4*)(src + 4);
            v[0] = f2bf(a.x); v[1] = f2bf(a.y); v[2] = f2bf(a.z); v[3] = f2bf(a.w);
            v[4] = f2bf(b.x); v[5] = f2bf(b.y); v[6] = f2bf(b.z); v[7] = f2bf(b.w);
        } else {
            v = (s8v)0;
        }
        *(s8v*)&Bs[r][c] = v;
    }
    __syncthreads();
    f4v acc[2][2] = {};
#pragma unroll
    for (int kk = 0; kk < 8; ++kk) {
        s8v af[2], bf_[2];
#pragma unroll
        for (int i = 0; i < 2; ++i)
            af[i] = *(const s8v*)&As[wm * 32 + i * 16 + (lane & 15)][kk * 32 + (lane >> 4) * 8];
#pragma unroll
        for (int j = 0; j < 2; ++j)
            bf_[j] = *(const s8v*)&Bs[wn * 32 + j * 16 + (lane & 15)][kk * 32 + (lane >> 4) * 8];
#pragma unroll
        for (int i = 0; i < 2; ++i)
#pragma unroll
            for (int j = 0; j < 2; ++j)
                acc[i][j] = __builtin_amdgcn_mfma_f32_16x16x32_bf16(af[i], bf_[j], acc[i][j], 0, 0, 0);
    }
#pragma unroll
    for (int i = 0; i < 2; ++i)
#pragma unroll
        for (int j = 0; j < 2; ++j) {
            int col = n0 + wn * 32 + j * 16 + (lane & 15);
            if (col >= N) continue;
            float bv = SPLIT ? 0.f : bias[col];
#pragma unroll
            for (int q = 0; q < 4; ++q) {
                int row = m0 + wm * 32 + i * 16 + (lane >> 4) * 4 + q;
                float v = acc[i][j][q] + bv;
                if (RELU) v = fmaxf(v, 0.f);
                if (SPLIT)      atomicAdd(&((float*)Cp)[(size_t)row * N + col], v);
                else if (OBF)   ((short*)Cp)[(size_t)row * N + col] = f2bf(v);
                else            ((float*)Cp)[(size_t)row * N + col] = v;
            }
        }
}

// ---------------------------------------------------------------------------
// bf16 MFMA GEMM (validated): C_bf16 = A_bf16 @ W_bf16^T + bias. 128x128 tile.
// Used for the big cross K/V projection (16384x512x256).
// ---------------------------------------------------------------------------
__global__ __launch_bounds__(256) void gemm_bf16_kernel(const short* __restrict__ A,
                                                        const short* __restrict__ W,
                                                        const float* __restrict__ bias,
                                                        short* __restrict__ C,
                                                        int M, int N, int K)
{
    __shared__ short As[128][40];
    __shared__ short Bs[128][40];
    const int tid = threadIdx.x;
    const int lane = tid & 63, wave = tid >> 6;
    const int wm = wave >> 1, wn = wave & 1;
    const int m0 = blockIdx.y * 128, n0 = blockIdx.x * 128;
    f4v acc[4][4] = {};
    for (int k0 = 0; k0 < K; k0 += 32) {
#pragma unroll
        for (int p = 0; p < 2; ++p) {
            int ci = tid + p * 256;
            int r = ci >> 2, c = (ci & 3) * 8;
            *(s8v*)&As[r][c] = *(const s8v*)&A[(size_t)(m0 + r) * K + k0 + c];
            *(s8v*)&Bs[r][c] = *(const s8v*)&W[(size_t)(n0 + r) * K + k0 + c];
        }
        __syncthreads();
        s8v af[4], bfr[4];
#pragma unroll
        for (int i = 0; i < 4; ++i)
            af[i] = *(const s8v*)&As[wm * 64 + i * 16 + (lane & 15)][(lane >> 4) * 8];
#pragma unroll
        for (int j = 0; j < 4; ++j)
            bfr[j] = *(const s8v*)&Bs[wn * 64 + j * 16 + (lane & 15)][(lane >> 4) * 8];
#pragma unroll
        for (int i = 0; i < 4; ++i)
#pragma unroll
            for (int j = 0; j < 4; ++j)
                acc[i][j] = __builtin_amdgcn_mfma_f32_16x16x32_bf16(af[i], bfr[j], acc[i][j], 0, 0, 0);
        __syncthreads();
    }
#pragma unroll
    for (int i = 0; i < 4; ++i)
#pragma unroll
        for (int j = 0; j < 4; ++j) {
            int col = n0 + wn * 64 + j * 16 + (lane & 15);
            float bv = bias[col];
#pragma unroll
            for (int q = 0; q < 4; ++q) {
                int row = m0 + wm * 64 + i * 16 + (lane >> 4) * 4 + q;
                C[(size_t)row * N + col] = f2bf(acc[i][j][q] + bv);
            }
        }
}

// ---------------------------------------------------------------------------
// cross scores (validated): Sc[bh][l][s] = scale * dot64(qb[l], K[s]), fp32 out
// ---------------------------------------------------------------------------
__global__ __launch_bounds__(256) void scores_bf16_kernel(const short* __restrict__ Q,
                                                          const short* __restrict__ kvb,
                                                          float* __restrict__ Sc,
                                                          float scale)
{
    __shared__ short Qs[128][72];
    __shared__ short Ks[128][72];
    const int tid = threadIdx.x;
    const int lane = tid & 63, wave = tid >> 6;
    const int wm = wave >> 1, wn = wave & 1;
    const int bh = blockIdx.z, b = bh >> 2, h = bh & 3;
    const int l0 = blockIdx.y * 128, s0 = blockIdx.x * 128;
#pragma unroll
    for (int p = 0; p < 4; ++p) {
        int ci = tid + p * 256;
        int r = ci >> 3, c = (ci & 7) * 8;
        *(s8v*)&Qs[r][c] = *(const s8v*)&Q[((size_t)(l0 + r) * BB + b) * D + h * HD + c];
        *(s8v*)&Ks[r][c] = *(const s8v*)&kvb[((size_t)b * S_MEM + s0 + r) * 512 + h * HD + c];
    }
    __syncthreads();
    f4v acc[4][4] = {};
#pragma unroll
    for (int kk = 0; kk < 2; ++kk) {
        s8v af[4], bfr[4];
#pragma unroll
        for (int i = 0; i < 4; ++i)
            af[i] = *(const s8v*)&Qs[wm * 64 + i * 16 + (lane & 15)][kk * 32 + (lane >> 4) * 8];
#pragma unroll
        for (int j = 0; j < 4; ++j)
            bfr[j] = *(const s8v*)&Ks[wn * 64 + j * 16 + (lane & 15)][kk * 32 + (lane >> 4) * 8];
#pragma unroll
        for (int i = 0; i < 4; ++i)
#pragma unroll
            for (int j = 0; j < 4; ++j)
                acc[i][j] = __builtin_amdgcn_mfma_f32_16x16x32_bf16(af[i], bfr[j], acc[i][j], 0, 0, 0);
    }
#pragma unroll
    for (int i = 0; i < 4; ++i)
#pragma unroll
        for (int q = 0; q < 4; ++q) {
            int l = l0 + wm * 64 + i * 16 + (lane >> 4) * 4 + q;
            size_t rowoff = ((size_t)bh * LT + l) * S_MEM;
#pragma unroll
            for (int j = 0; j < 4; ++j) {
                int s = s0 + wn * 64 + j * 16 + (lane & 15);
                Sc[rowoff + s] = acc[i][j][q] * scale;
            }
        }
}

// ---------------------------------------------------------------------------
// self scores (bf16 MFMA): Sc[bh][l][s] = scale * dot64(Q[l], K[s]), Sk=LT.
// Q/K from qkvb [NTOK][768]: Q cols [0,256), K cols [256,512). 64x64 tile.
// ---------------------------------------------------------------------------
__global__ __launch_bounds__(256) void scores_self_kernel(const short* __restrict__ qkvb,
                                                          float* __restrict__ Sc,
                                                          float scale)
{
    __shared__ short Qs[64][72];
    __shared__ short Ks[64][72];
    const int tid = threadIdx.x;
    const int lane = tid & 63, wave = tid >> 6;
    const int wm = wave >> 1, wn = wave & 1;
    const int bh = blockIdx.z, b = bh >> 2, h = bh & 3;
    const int l0 = blockIdx.y * 64, s0 = blockIdx.x * 64;
#pragma unroll
    for (int p = 0; p < 2; ++p) {
        int idx = p * 2048 + tid * 8;
        int r = idx >> 6, c = idx & 63;
        *(s8v*)&Qs[r][c] = *(const s8v*)&qkvb[((size_t)(l0 + r) * BB + b) * 768 + h * HD + c];
        *(s8v*)&Ks[r][c] = *(const s8v*)&qkvb[((size_t)(s0 + r) * BB + b) * 768 + 256 + h * HD + c];
    }
    __syncthreads();
    f4v acc[2][2] = {};
#pragma unroll
    for (int kk = 0; kk < 2; ++kk) {
        s8v af[2], bf_[2];
#pragma unroll
        for (int i = 0; i < 2; ++i)
            af[i] = *(const s8v*)&Qs[wm * 32 + i * 16 + (lane & 15)][kk * 32 + (lane >> 4) * 8];
#pragma unroll
        for (int j = 0; j < 2; ++j)
            bf_[j] = *(const s8v*)&Ks[wn * 32 + j * 16 + (lane & 15)][kk * 32 + (lane >> 4) * 8];
#pragma unroll
        for (int i = 0; i < 2; ++i)
#pragma unroll
            for (int j = 0; j < 2; ++j)
                acc[i][j] = __builtin_amdgcn_mfma_f32_16x16x32_bf16(af[i], bf_[j], acc[i][j], 0, 0, 0);
    }
#pragma unroll
    for (int i = 0; i < 2; ++i)
#pragma unroll
        for (int q = 0; q < 4; ++q) {
            int l = l0 + wm * 32 + i * 16 + (lane >> 4) * 4 + q;
            size_t rowoff = ((size_t)bh * LT + l) * LT;
#pragma unroll
            for (int j = 0; j < 2; ++j) {
                int s = s0 + wn * 32 + j * 16 + (lane & 15);
                Sc[rowoff + s] = acc[i][j][q] * scale;
            }
        }
}

// ---------------------------------------------------------------------------
// V transpose (parameterized): Vt[bh][d][s] <- src[b*bStride + vOff + h*64 + s*sStride + d]
// cross: src=kvb  bStride=S_MEM*512 vOff=256 sStride=512  Stot=S_MEM
// self:  src=qkvb bStride=768       vOff=512 sStride=1536 Stot=LT
// ---------------------------------------------------------------------------
__global__ __launch_bounds__(256) void vtrans_kernel(const short* __restrict__ src,
                                                     long bStride, int sStride, int vOff,
                                                     short* __restrict__ Vt, int Stot)
{
    __shared__ short t[64][72];
    int s0 = blockIdx.x * 64, bh = blockIdx.y, b = bh >> 2, h = bh & 3;
    const short* sb = src + (size_t)b * bStride + vOff + h * HD;
    int tid = threadIdx.x;
#pragma unroll
    for (int p = 0; p < 2; ++p) {
        int r = (tid >> 3) + p * 32;
        int c = (tid & 7) * 8;
        *(s8v*)&t[r][c] = *(const s8v*)&sb[(size_t)(s0 + r) * sStride + c];
    }
    __syncthreads();
    int d = tid >> 2, s1 = (tid & 3) * 16;
    short v[16];
#pragma unroll
    for (int j = 0; j < 16; ++j) v[j] = t[s1 + j][d];
    *(s8v*)&Vt[((size_t)bh * HD + d) * Stot + s0 + s1] = *(s8v*)&v[0];
    *(s8v*)&Vt[((size_t)bh * HD + d) * Stot + s0 + s1 + 8] = *(s8v*)&v[8];
}

// ---------------------------------------------------------------------------
// PV (bf16 MFMA, split-K atomics, parameterized Sk/chunk):
// O[l,b,h*64+d] += sum_s P[bh][l][s] * Vt[bh][d][s]; P fp32 cvt in staging.
// block tile 128(l) x 64(d); grid (Sk/chunk, LT/128, 8); O zeroed beforehand.
// ---------------------------------------------------------------------------
__global__ __launch_bounds__(256) void pv_bf16_kernel(const float* __restrict__ P,
                                                      const short* __restrict__ Vt,
                                                      float* __restrict__ O,
                                                      int Sk, int chunk)
{
    __shared__ short Ps[128][40];
    __shared__ short Vs[64][40];
    const int tid = threadIdx.x;
    const int lane = tid & 63, wm = tid >> 6;
    const int bh = blockIdx.z, b = bh >> 2, h = bh & 3;
    const int l0 = blockIdx.y * 128;
    const int sBeg = blockIdx.x * chunk;
    f4v acc[2][4] = {};
    for (int ks = 0; ks < chunk; ks += 32) {
#pragma unroll
        for (int p = 0; p < 2; ++p) {
            int ci = tid + p * 256;
            int r = ci >> 2, c = (ci & 3) * 8;
            const float* src = &P[((size_t)bh * LT + l0 + r) * Sk + sBeg + ks + c];
            float4 a = *(const float4*)src;
            float4 bq = *(const float4*)(src + 4);
            s8v v;
            v[0] = f2bf(a.x); v[1] = f2bf(a.y); v[2] = f2bf(a.z); v[3] = f2bf(a.w);
            v[4] = f2bf(bq.x); v[5] = f2bf(bq.y); v[6] = f2bf(bq.z); v[7] = f2bf(bq.w);
            *(s8v*)&Ps[r][c] = v;
        }
        {
            int r = tid >> 2, c = (tid & 3) * 8;
            *(s8v*)&Vs[r][c] = *(const s8v*)&Vt[((size_t)bh * HD + r) * Sk + sBeg + ks + c];
        }
        __syncthreads();
        s8v af[2], bfr[4];
#pragma unroll
        for (int i = 0; i < 2; ++i)
            af[i] = *(const s8v*)&Ps[wm * 32 + i * 16 + (lane & 15)][(lane >> 4) * 8];
#pragma unroll
        for (int j = 0; j < 4; ++j)
            bfr[j] = *(const s8v*)&Vs[j * 16 + (lane & 15)][(lane >> 4) * 8];
#pragma unroll
        for (int i = 0; i < 2; ++i)
#pragma unroll
            for (int j = 0; j < 4; ++j)
                acc[i][j] = __builtin_amdgcn_mfma_f32_16x16x32_bf16(af[i], bfr[j], acc[i][j], 0, 0, 0);
        __syncthreads();
    }
#pragma unroll
    for (int i = 0; i < 2; ++i)
#pragma unroll
        for (int q = 0; q < 4; ++q) {
            int l = l0 + wm * 32 + i * 16 + (lane >> 4) * 4 + q;
#pragma unroll
            for (int j = 0; j < 4; ++j) {
                int d = j * 16 + (lane & 15);
                atomicAdd(&O[((size_t)l * BB + b) * D + h * HD + d], acc[i][j][q]);
            }
        }
}

// ---------------------------------------------------------------------------
// row softmax fp32 in place. NIT=Sk/256. causal masks s>l (writes 0 there).
// ---------------------------------------------------------------------------
template <int NIT>
__global__ __launch_bounds__(256) void softmax_kernel(float* __restrict__ Sc, int Sk, int causal)
{
    int l = blockIdx.x, bh = blockIdx.y;
    float* row = Sc + ((size_t)bh * LT + l) * Sk;
    int valid = causal ? (l + 1) : Sk;
    int tid = threadIdx.x;
    float vals[NIT];
    float m = -3.0e38f;
#pragma unroll
    for (int i = 0; i < NIT; ++i) {
        int idx = tid + i * 256;
        float v = (idx < valid) ? row[idx] : -3.0e38f;
        vals[i] = v;
        m = fmaxf(m, v);
    }
#pragma unroll
    for (int off = 32; off; off >>= 1) m = fmaxf(m, __shfl_xor(m, off));
    __shared__ float smax[4];
    __shared__ float ssum[4];
    int lane = tid & 63, w = tid >> 6;
    if (lane == 0) smax[w] = m;
    __syncthreads();
    m = fmaxf(fmaxf(smax[0], smax[1]), fmaxf(smax[2], smax[3]));
    float s = 0.f;
#pragma unroll
    for (int i = 0; i < NIT; ++i) {
        int idx = tid + i * 256;
        float e = (idx < valid) ? __expf(vals[i] - m) : 0.f;
        vals[i] = e;
        s += e;
    }
#pragma unroll
    for (int off = 32; off; off >>= 1) s += __shfl_xor(s, off);
    if (lane == 0) ssum[w] = s;
    __syncthreads();
    s = ssum[0] + ssum[1] + ssum[2] + ssum[3];
    float inv = 1.f / s;
#pragma unroll
    for (int i = 0; i < NIT; ++i) {
        int idx = tid + i * 256;
        row[idx] = vals[i] * inv;
    }
}

// ---------------------------------------------------------------------------
// tgt = LayerNorm(tgt + t2 [+ eb]) * g + beta ; also writes bf16 shadow
// ---------------------------------------------------------------------------
__global__ __launch_bounds__(256) void ln_kernel(float* __restrict__ tgt,
                                                 short* __restrict__ tgt_bf,
                                                 const float* __restrict__ t2,
                                                 const float* __restrict__ eb,
                                                 const float* __restrict__ g,
                                                 const float* __restrict__ beta)
{
    int r = blockIdx.x, d = threadIdx.x;
    float x = tgt[(size_t)r * D + d] + t2[(size_t)r * D + d];
    if (eb) x += eb[d];
    float v1 = x, v2 = x * x;
#pragma unroll
    for (int off = 32; off; off >>= 1) {
        v1 += __shfl_xor(v1, off);
        v2 += __shfl_xor(v2, off);
    }
    __shared__ float s1[4], s2[4];
    int lane = d & 63, w = d >> 6;
    if (lane == 0) { s1[w] = v1; s2[w] = v2; }
    __syncthreads();
    float sum = s1[0] + s1[1] + s1[2] + s1[3];
    float sums = s2[0] + s2[1] + s2[2] + s2[3];
    float mean = sum * (1.f / 256.f);
    float var = sums * (1.f / 256.f) - mean * mean;
    float y = (x - mean) * rsqrtf(var + EPS) * g[d] + beta[d];
    tgt[(size_t)r * D + d] = y;
    tgt_bf[(size_t)r * D + d] = f2bf(y);
}

// ---------------------------------------------------------------------------
extern "C" void kernel_launch(void* const* d_in, const int* in_sizes, int n_in,
                              void* d_out, int out_size, void* d_ws, size_t ws_size,
                              hipStream_t stream)
{
    (void)in_sizes; (void)n_in; (void)out_size; (void)ws_size;
    const int*   tokens   = (const int*)d_in[0];
    const float* features = (const float*)d_in[1];
    const float* emb      = (const float*)d_in[2];
    const float* sa_w     = (const float*)d_in[3];
    const float* sa_b     = (const float*)d_in[4];
    const float* ca_w     = (const float*)d_in[5];
    const float* ca_b     = (const float*)d_in[6];
    const float* ln_g     = (const float*)d_in[7];
    const float* ln_b     = (const float*)d_in[8];
    const float* ff_w1    = (const float*)d_in[9];
    const float* ff_b1    = (const float*)d_in[10];
    const float* ff_w2    = (const float*)d_in[11];
    const float* ff_b2    = (const float*)d_in[12];
    const float* out_w    = (const float*)d_in[13];
    const float* out_b    = (const float*)d_in[14];
    float* out = (float*)d_out;

    // workspace layout (~104 MB total; proven >= 123 MB available)
    float* ws = (float*)d_ws;
    float* sc    = ws;                         // 16,777,216 f (64MB) scores
    float* tgtb  = sc + 16777216;              // 131,072 f
    float* qkv   = tgtb + 131072;              // 393,216 f (aliased as bf16 qkvb)
    float* qc    = qkv + 393216;               // 131,072 f (unused, layout stable)
    float* obuf  = qc + 131072;                // 131,072 f
    float* t2b   = obuf + 131072;              // 131,072 f
    float* hbuf  = t2b + 131072;               // 524,288 f (aliased as bf16 hbufb)
    short* membb = (short*)(hbuf + 524288);    // 4,194,304 s (8MB)
    short* kvb   = membb + 4194304;            // 8,388,608 s (16MB)
    short* vtb   = kvb + 8388608;              // 4,194,304 s (8MB; self reuses head)
    short* qb    = vtb + 4194304;              // 131,072 s
    short* kvwb  = qb + 131072;                // 1,048,576 s (2MB) cross KV weights bf16
    short* tgtbb = kvwb + 1048576;             // 131,072 s bf16 residual shadow
    short* qkvb  = (short*)qkv;                // 512x768 bf16
    short* hbufb = (short*)hbuf;               // 512x1024 bf16

    const float scale = 0.125f;  // hd^-0.5

    build_mem_kernel<<<dim3(FW / 32, D / 32, BB * FH), dim3(32, 8), 0, stream>>>(features, membb);
    embed_kernel<<<NTOK, D, 0, stream>>>(tokens, emb, tgtb, tgtbb);
    for (int i = 0; i < NL; ++i)   // cross K/V weight blocks (512x256 each) to bf16
        cvt_kernel<<<(2 * D * D) / (256 * 8), 256, 0, stream>>>(
            ca_w + (size_t)i * 4 * D * D + D * D, kvwb + (size_t)i * 2 * D * D, 2 * D * D);

    for (int i = 0; i < NL; ++i) {
        const float* saw = sa_w + (size_t)i * 4 * D * D;
        const float* sab = sa_b + (size_t)i * 4 * D;
        const float* caw = ca_w + (size_t)i * 4 * D * D;
        const float* cab = ca_b + (size_t)i * 4 * D;
        const short* kvw = kvwb + (size_t)i * 2 * D * D;
        const float* lg  = ln_g + (size_t)i * 3 * D;
        const float* lb  = ln_b + (size_t)i * 3 * D;

        // ---- self attention (causal, bf16 MFMA) ----
        gemm_small_kernel<1, 0, 0, 1><<<dim3(768 / 64, NTOK / 64), 256, 0, stream>>>(
            tgtbb, saw, sab, qkvb, NTOK, 768, D);
        vtrans_kernel<<<dim3(LT / 64, BB * NH), 256, 0, stream>>>(
            qkvb, 768L, 2 * 768, 512, vtb, LT);
        scores_self_kernel<<<dim3(LT / 64, LT / 64, BB * NH), 256, 0, stream>>>(
            qkvb, sc, scale);
        softmax_kernel<1><<<dim3(LT, BB * NH), 256, 0, stream>>>(sc, LT, 1);
        hipMemsetAsync(obuf, 0, (size_t)NTOK * D * sizeof(float), stream);
        pv_bf16_kernel<<<dim3(2, LT / 128, BB * NH), 256, 0, stream>>>(
            sc, vtb, obuf, LT, 128);
        gemm_small_kernel<0, 0, 0, 0><<<dim3(D / 64, NTOK / 64), 256, 0, stream>>>(
            obuf, saw + 3 * D * D, sab + 3 * D, t2b, NTOK, D, D);
        ln_kernel<<<NTOK, D, 0, stream>>>(tgtb, tgtbb, t2b, nullptr, lg, lb);

        // ---- cross attention (bf16 MFMA) ----
        gemm_small_kernel<1, 0, 0, 1><<<dim3(D / 64, NTOK / 64), 256, 0, stream>>>(
            tgtbb, caw, cab, qb, NTOK, D, D);
        gemm_bf16_kernel<<<dim3(512 / 128, MEMROWS / 128), 256, 0, stream>>>(
            membb, kvw, cab + D, kvb, MEMROWS, 512, D);
        vtrans_kernel<<<dim3(S_MEM / 64, BB * NH), 256, 0, stream>>>(
            kvb, (long)S_MEM * 512, 512, 256, vtb, S_MEM);
        scores_bf16_kernel<<<dim3(S_MEM / 128, LT / 128, BB * NH), 256, 0, stream>>>(
            qb, kvb, sc, scale);
        softmax_kernel<32><<<dim3(LT, BB * NH), 256, 0, stream>>>(sc, S_MEM, 0);
        hipMemsetAsync(obuf, 0, (size_t)NTOK * D * sizeof(float), stream);
        pv_bf16_kernel<<<dim3(S_MEM / 512, LT / 128, BB * NH), 256, 0, stream>>>(
            sc, vtb, obuf, S_MEM, 512);
        gemm_small_kernel<0, 0, 0, 0><<<dim3(D / 64, NTOK / 64), 256, 0, stream>>>(
            obuf, caw + 3 * D * D, cab + 3 * D, t2b, NTOK, D, D);
        ln_kernel<<<NTOK, D, 0, stream>>>(tgtb, tgtbb, t2b, nullptr, lg + D, lb + D);

        // ---- FFN (bf16 MFMA; w2 split-K with fp32 atomics, bias folded into LN) ----
        gemm_small_kernel<1, 1, 0, 1><<<dim3(DFF / 64, NTOK / 64), 256, 0, stream>>>(
            tgtbb, ff_w1 + (size_t)i * DFF * D, ff_b1 + (size_t)i * DFF, hbufb, NTOK, DFF, D);
        hipMemsetAsync(t2b, 0, (size_t)NTOK * D * sizeof(float), stream);
        gemm_small_kernel<1, 0, 1, 0><<<dim3(D / 64, NTOK / 64, DFF / 256), 256, 0, stream>>>(
            hbufb, ff_w2 + (size_t)i * D * DFF, nullptr, t2b, NTOK, D, DFF);
        ln_kernel<<<NTOK, D, 0, stream>>>(tgtb, tgtbb, t2b,
                                          ff_b2 + (size_t)i * D, lg + 2 * D, lb + 2 * D);
    }

    gemm_small_kernel<1, 0, 0, 0><<<dim3((VOCAB + 63) / 64, NTOK / 64), 256, 0, stream>>>(
        tgtbb, out_w, out_b, out, NTOK, VOCAB, D);
}